// Round 12
// baseline (557.702 us; speedup 1.0000x reference)
//
#include <hip/hip_runtime.h>
#include <hip/hip_cooperative_groups.h>

namespace cg = cooperative_groups;
typedef unsigned int u32;

// ---------------- FFT-based reverb (R12: single cooperative kernel) ----------------
// out[t] = sum_k audio[t+k] ir[k], t in [0,480000); M = 2^20 circular == linear.
// z = a + i*b ; Z = F[z]; A=(Z[f]+conj(Z[M-f]))/2, B=(Z[f]-conj(Z[M-f]))/(2i)
// S = A*conj(B); out = Re( F[ conj(S)/M ] ).
// Four-step M = 1024*1024 (verified R8-R11); radix-4 swizzled Stockham in LDS.
// R12: phases A..E fused with grid.sync() (kills 4 launch gaps + 4 table restages).

constexpr int N_AUDIO = 480000;
constexpr int M_FFT   = 1048576;      // 2^20

constexpr size_t OFF_C0   = 0;                    // 8 MB float2
constexpr size_t OFF_C1   = (size_t)M_FFT * 8;    // 8 MB float2
constexpr size_t OFF_SLOT = OFF_C1 + (size_t)M_FFT * 8;   // u32

#define SW(i) ((i) + ((i) >> 4))      // LDS pad swizzle
constexpr int LSZ = 1088;             // SW(1023)=1086

// ---- compile-time twiddle ROM (constexpr Taylor, double precision) ----
struct F2 { float x, y; };
constexpr double D_PI = 3.14159265358979323846264338327950288;
constexpr double tay_sin(double x) {
    double t = x, s = x, x2 = x * x;
    for (int k = 1; k <= 11; ++k) { t *= -x2 / (double)((2 * k) * (2 * k + 1)); s += t; }
    return s;
}
constexpr double tay_cos(double x) {
    double t = 1.0, s = 1.0, x2 = x * x;
    for (int k = 1; k <= 11; ++k) { t *= -x2 / (double)((2 * k - 1) * (2 * k)); s += t; }
    return s;
}
struct Tab { F2 v[1024]; };
constexpr Tab make_t1() {   // W_1024^j, arg centered to [-pi,pi)
    Tab tb{};
    for (int j = 0; j < 1024; ++j) {
        int jj = (j < 512) ? j : j - 1024;
        double a = -2.0 * D_PI * (double)jj / 1024.0;
        tb.v[j] = F2{(float)tay_cos(a), (float)tay_sin(a)};
    }
    return tb;
}
constexpr Tab make_t2() {   // W_M^j
    Tab tb{};
    for (int j = 0; j < 1024; ++j) {
        double a = -2.0 * D_PI * (double)j / 1048576.0;
        tb.v[j] = F2{(float)tay_cos(a), (float)tay_sin(a)};
    }
    return tb;
}
__device__ constexpr Tab ROM_T1 = make_t1();
__device__ constexpr Tab ROM_T2 = make_t2();

__device__ __forceinline__ float2 ldrom(const Tab& tb, int i) {
    F2 f = tb.v[i];
    return make_float2(f.x, f.y);
}
__device__ __forceinline__ float2 cmul(float2 a, float2 b) {
    return make_float2(a.x * b.x - a.y * b.y, a.x * b.y + a.y * b.x);
}
__device__ __forceinline__ void stage_tabs(float2* lt1, float2* lt2, int t) {
    #pragma unroll
    for (int q = 0; q < 4; ++q) {
        int i = t + 256 * q;
        lt1[i] = ldrom(ROM_T1, i);
        lt2[i] = ldrom(ROM_T2, i);
    }
}

// Radix-4 Stockham FFT-1024, 2 rows, 256 threads, 5 stages, result in B0 (scr).
__device__ __forceinline__ void fft1024_r4(float2 (*A0)[LSZ], float2 (*B0)[LSZ],
                                           const float2* lt1, int t) {
    float2 (*A)[LSZ] = A0;
    float2 (*B)[LSZ] = B0;
    #pragma unroll
    for (int s = 0; s < 5; ++s) {
        const int L  = 1 << (2 * s);
        const int k  = t & (L - 1);
        const int p0 = 4 * t - 3 * k;
        const float2 w  = lt1[k << (9 - 2 * s)];   // e^{-2pi i k/(2L)}
        const float2 w2 = lt1[k << (8 - 2 * s)];   // e^{-2pi i k/(4L)}
        #pragma unroll
        for (int j = 0; j < 2; ++j) {
            float2 x0 = A[j][SW(t)];
            float2 x2 = A[j][SW(t + 256)];
            float2 x1 = A[j][SW(t + 512)];
            float2 x3 = A[j][SW(t + 768)];
            float2 wx1 = cmul(w, x1), wx3 = cmul(w, x3);
            float2 u0 = make_float2(x0.x + wx1.x, x0.y + wx1.y);
            float2 u1 = make_float2(x0.x - wx1.x, x0.y - wx1.y);
            float2 u2 = make_float2(x2.x + wx3.x, x2.y + wx3.y);
            float2 u3 = make_float2(x2.x - wx3.x, x2.y - wx3.y);
            float2 a2 = cmul(w2, u2);
            float2 a3 = cmul(w2, u3);
            B[j][SW(p0)]         = make_float2(u0.x + a2.x, u0.y + a2.y);
            B[j][SW(p0 + L)]     = make_float2(u1.x + a3.y, u1.y - a3.x); // u1 - i*a3
            B[j][SW(p0 + 2*L)]   = make_float2(u0.x - a2.x, u0.y - a2.y);
            B[j][SW(p0 + 3*L)]   = make_float2(u1.x - a3.y, u1.y + a3.x); // u1 + i*a3
        }
        __syncthreads();
        float2 (*tmp)[LSZ] = A; A = B; B = tmp;
    }
}

// ---- phase A: transform-1 pass1 + input pack, rows r0,r0+1
__device__ __forceinline__ void phaseA(const float* __restrict__ a, const float* __restrict__ b,
                                       float2* __restrict__ outb,
                                       float2 (*rows)[LSZ], float2 (*scr)[LSZ],
                                       const float2* lt1, const float2* lt2, int t, int r0) {
    #pragma unroll
    for (int q = 0; q < 4; ++q) {
        int c = t + 256 * q;
        int base = c * 1024 + r0;
        float2 av = make_float2(0.f, 0.f), bv = make_float2(0.f, 0.f);
        if (c < 468 || (c == 468 && r0 < 768)) av = *(const float2*)(a + base);
        if (c < 234 || (c == 234 && r0 < 384)) bv = *(const float2*)(b + base);
        rows[0][SW(c)] = make_float2(av.x, bv.x);
        rows[1][SW(c)] = make_float2(av.y, bv.y);
    }
    __syncthreads();
    fft1024_r4(rows, scr, lt1, t);
    #pragma unroll
    for (int q = 0; q < 4; ++q) {
        int k1 = t + 256 * q;
        #pragma unroll
        for (int j = 0; j < 2; ++j) {
            int e = (r0 + j) * k1;                        // < 2^20
            float2 w = cmul(lt1[e >> 10], lt2[e & 1023]); // W_M^e
            outb[(r0 + j) * 1024 + k1] = cmul(w, scr[j][SW(k1)]);
        }
    }
}

// ---- phase B: transform-1 pass2 + pointwise, Hermitian pair {bidx, 1024-bidx}
__device__ __forceinline__ void phaseB(const float2* __restrict__ in, float2* __restrict__ spec,
                                       float2 (*cols)[LSZ], float2 (*scr)[LSZ],
                                       const float2* lt1, int t, int bidx) {
    const int cA = (bidx == 0) ? 0   : bidx;
    const int cB = (bidx == 0) ? 512 : 1024 - bidx;
    #pragma unroll
    for (int q = 0; q < 4; ++q) {
        int r = t + 256 * q;
        cols[0][SW(r)] = in[r * 1024 + cA];
        cols[1][SW(r)] = in[r * 1024 + cB];
    }
    __syncthreads();
    fft1024_r4(cols, scr, lt1, t);
    const float invM = 1.0f / 1048576.0f;
    #pragma unroll
    for (int q = 0; q < 4; ++q) {
        int k2 = t + 256 * q;
        #pragma unroll
        for (int j = 0; j < 2; ++j) {
            float2 z1 = scr[j][SW(k2)];                 // Z[f], f = c_j + 1024*k2
            float2 z2;                                  // Z[M-f]
            if (bidx == 0) z2 = (j == 0) ? scr[0][SW((1024 - k2) & 1023)]
                                         : scr[1][SW(1023 - k2)];
            else           z2 = scr[j ^ 1][SW(1023 - k2)];
            float2 Af  = make_float2(0.5f * (z1.x + z2.x), 0.5f * (z1.y - z2.y));
            float2 cBf = make_float2(0.5f * (z1.y + z2.y), 0.5f * (z1.x - z2.x)); // conj(B)
            float2 S   = cmul(Af, cBf);
            int cc = (j == 0) ? cA : cB;
            spec[cc * 1024 + k2] = make_float2(S.x * invM, -S.y * invM);  // conj(S)/M
        }
    }
}

// ---- phase C: transform-2 pass1 (contiguous s-layout rows, float4)
__device__ __forceinline__ void phaseC(const float2* __restrict__ in, float2* __restrict__ outb,
                                       float2 (*rows)[LSZ], float2 (*scr)[LSZ],
                                       const float2* lt1, const float2* lt2, int t, int r0) {
    const float4* inv4 = (const float4*)(in + (size_t)r0 * 1024);
    #pragma unroll
    for (int q = 0; q < 4; ++q) {
        int i2 = t + 256 * q;               // complex 2*i2, 2*i2+1
        float4 v = inv4[i2];
        int j = i2 >> 9, c = (i2 & 511) * 2;
        rows[j][SW(c)]     = make_float2(v.x, v.y);
        rows[j][SW(c + 1)] = make_float2(v.z, v.w);
    }
    __syncthreads();
    fft1024_r4(rows, scr, lt1, t);
    #pragma unroll
    for (int q = 0; q < 4; ++q) {
        int k1 = t + 256 * q;
        #pragma unroll
        for (int j = 0; j < 2; ++j) {
            int e = (r0 + j) * k1;
            float2 w = cmul(lt1[e >> 10], lt2[e & 1023]);
            outb[(r0 + j) * 1024 + k1] = cmul(w, scr[j][SW(k1)]);
        }
    }
}

// ---- phase D: transform-2 pass2, cols {c0,c0+1}; writes rawT (transposed) + abs-max
__device__ __forceinline__ void phaseD(const float2* __restrict__ in, float* __restrict__ rawT,
                                       u32* __restrict__ slot,
                                       float2 (*cols)[LSZ], float2 (*scr)[LSZ],
                                       const float2* lt1, float* wmax, int t, int c0) {
    #pragma unroll
    for (int q = 0; q < 4; ++q) {
        int r = t + 256 * q;
        float4 v = *(const float4*)(in + (size_t)r * 1024 + c0);
        cols[0][SW(r)] = make_float2(v.x, v.y);
        cols[1][SW(r)] = make_float2(v.z, v.w);
    }
    __syncthreads();
    fft1024_r4(cols, scr, lt1, t);
    float m = 0.0f;
    #pragma unroll
    for (int q = 0; q < 4; ++q) {
        int k2 = t + 256 * q;
        #pragma unroll
        for (int j = 0; j < 2; ++j) {
            int ot = c0 + j + (k2 << 10);
            if (ot < N_AUDIO) {
                float v = scr[j][SW(k2)].x;
                rawT[(c0 + j) * 512 + k2] = v;       // contiguous along k2
                m = fmaxf(m, fabsf(v));
            }
        }
    }
    for (int off = 32; off > 0; off >>= 1) m = fmaxf(m, __shfl_down(m, off, 64));
    if ((t & 63) == 0) wmax[t >> 6] = m;
    __syncthreads();
    if (t == 0) {
        float bm = fmaxf(fmaxf(wmax[0], wmax[1]), fmaxf(wmax[2], wmax[3]));
        atomicMax(slot, __float_as_uint(bm));
    }
}

// ---- phase E: tiled transpose + normalize; block w handles 64(c) x 16(k2) chunk
__device__ __forceinline__ void phaseE(const float* __restrict__ rawT,
                                       const u32* __restrict__ slot,
                                       float* __restrict__ out,
                                       float* tileRaw, int t, int w) {
    float (*tile)[17] = (float(*)[17])tileRaw;       // 64x17 floats = 4352 B
    const int c0  = (w & 15) * 64;
    const int kq0 = (w >> 4) * 16;
    const int cl = t >> 2, kk4 = (t & 3) * 4;
    float4 v = *(const float4*)(rawT + (size_t)(c0 + cl) * 512 + kq0 + kk4);
    tile[cl][kk4 + 0] = v.x;
    tile[cl][kk4 + 1] = v.y;
    tile[cl][kk4 + 2] = v.z;
    tile[cl][kk4 + 3] = v.w;
    __syncthreads();
    const float inv = 1.0f / __uint_as_float(*(volatile const u32*)slot);
    const int cw = t & 63, kq = t >> 6;
    #pragma unroll
    for (int i = 0; i < 4; ++i) {
        int kk = kq * 4 + i;
        int o = (kq0 + kk) * 1024 + c0 + cw;
        if (o < N_AUDIO) out[o] = tile[cw][kk] * inv;
    }
}

// ================= fused cooperative kernel =================
__global__ __launch_bounds__(256) void reverb_fused(const float* __restrict__ a,
                                                    const float* __restrict__ b,
                                                    float2* __restrict__ cb0,
                                                    float2* __restrict__ cb1,
                                                    u32* __restrict__ slot,
                                                    float* __restrict__ out) {
    cg::grid_group grid = cg::this_grid();
    __shared__ float2 buf0[2][LSZ], buf1[2][LSZ];    // 34,816 B
    __shared__ float2 lt1[1024], lt2[1024];          // 16,384 B
    __shared__ float  wmax[4];
    const int t   = threadIdx.x;
    const int bid = blockIdx.x;

    stage_tabs(lt1, lt2, t);
    if (bid == 0 && t == 0) *slot = 0u;

    phaseA(a, b, cb1, buf0, buf1, lt1, lt2, t, bid * 2);
    __threadfence();  grid.sync();
    phaseB(cb1, cb0, buf0, buf1, lt1, t, bid);
    __threadfence();  grid.sync();
    phaseC(cb0, cb1, buf0, buf1, lt1, lt2, t, bid * 2);
    __threadfence();  grid.sync();
    phaseD(cb1, (float*)cb0, slot, buf0, buf1, lt1, wmax, t, bid * 2);
    __threadfence();  grid.sync();
    phaseE((const float*)cb0, slot, out, (float*)lt2, t, bid);   // tile aliases lt2
}

// ================= fallback: 5-kernel path (identical math) =================
__global__ __launch_bounds__(256) void kA(const float* __restrict__ a, const float* __restrict__ b,
                                          float2* __restrict__ outb, u32* __restrict__ slot) {
    __shared__ float2 buf0[2][LSZ], buf1[2][LSZ], lt1[1024], lt2[1024];
    const int t = threadIdx.x;
    if (blockIdx.x == 0 && t == 0) *slot = 0u;
    stage_tabs(lt1, lt2, t);
    phaseA(a, b, outb, buf0, buf1, lt1, lt2, t, blockIdx.x * 2);
}
__global__ __launch_bounds__(256) void kB(const float2* __restrict__ in, float2* __restrict__ spec) {
    __shared__ float2 buf0[2][LSZ], buf1[2][LSZ], lt1[1024];
    const int t = threadIdx.x;
    #pragma unroll
    for (int q = 0; q < 4; ++q) { int i = t + 256 * q; lt1[i] = ldrom(ROM_T1, i); }
    phaseB(in, spec, buf0, buf1, lt1, t, blockIdx.x);
}
__global__ __launch_bounds__(256) void kC(const float2* __restrict__ in, float2* __restrict__ outb) {
    __shared__ float2 buf0[2][LSZ], buf1[2][LSZ], lt1[1024], lt2[1024];
    const int t = threadIdx.x;
    stage_tabs(lt1, lt2, t);
    phaseC(in, outb, buf0, buf1, lt1, lt2, t, blockIdx.x * 2);
}
__global__ __launch_bounds__(256) void kD(const float2* __restrict__ in, float* __restrict__ rawT,
                                          u32* __restrict__ slot) {
    __shared__ float2 buf0[2][LSZ], buf1[2][LSZ], lt1[1024];
    __shared__ float wmax[4];
    const int t = threadIdx.x;
    #pragma unroll
    for (int q = 0; q < 4; ++q) { int i = t + 256 * q; lt1[i] = ldrom(ROM_T1, i); }
    phaseD(in, rawT, slot, buf0, buf1, lt1, wmax, t, blockIdx.x * 2);
}
__global__ __launch_bounds__(256) void kE(const float* __restrict__ rawT,
                                          const u32* __restrict__ slot, float* __restrict__ out) {
    __shared__ float tileRaw[64 * 17];
    phaseE(rawT, slot, out, tileRaw, threadIdx.x, blockIdx.x);
}

extern "C" void kernel_launch(void* const* d_in, const int* in_sizes, int n_in,
                              void* d_out, int out_size, void* d_ws, size_t ws_size,
                              hipStream_t stream) {
    const float* audio = (const float*)d_in[0];
    const float* ir    = (const float*)d_in[1];
    float* out = (float*)d_out;

    char* ws = (char*)d_ws;
    float2* cb0 = (float2*)(ws + OFF_C0);
    float2* cb1 = (float2*)(ws + OFF_C1);
    u32*    slot = (u32*)(ws + OFF_SLOT);

    void* args[] = {(void*)&audio, (void*)&ir, (void*)&cb0, (void*)&cb1,
                    (void*)&slot, (void*)&out};
    hipError_t err = hipLaunchCooperativeKernel((const void*)reverb_fused,
                                                dim3(512), dim3(256), args, 0, stream);
    if (err != hipSuccess) {
        // deterministic fallback: identical 5-kernel pipeline
        kA<<<512, 256, 0, stream>>>(audio, ir, cb1, slot);
        kB<<<512, 256, 0, stream>>>(cb1, cb0);
        kC<<<512, 256, 0, stream>>>(cb0, cb1);
        kD<<<512, 256, 0, stream>>>(cb1, (float*)cb0, slot);
        kE<<<512, 256, 0, stream>>>((const float*)cb0, slot, out);
    }
}

// Round 15
// 104.432 us; speedup vs baseline: 5.3403x; 5.3403x over previous
//
#include <hip/hip_runtime.h>

typedef unsigned int u32;

// ---------------- FFT-based reverb (R13: B+C fused producer-consumer) ----------------
// out[t] = sum_k audio[t+k] ir[k], t in [0,480000); M = 2^20 circular == linear.
// z = a + i*b ; Z = F[z]; A=(Z[f]+conj(Z[M-f]))/2, B=(Z[f]-conj(Z[M-f]))/(2i)
// S = A*conj(B); out = Re( F[ conj(S)/M ] ).
// Four-step M = 1024*1024 (verified R8-R11); radix-4 swizzled Stockham in LDS.
// R13: transform-1 pass2 + pointwise + transform-2 pass1 fused in ONE block:
// block bidx's pointwise output (spec rows {bidx, 1024-bidx}) is exactly the
// s-layout rows transform-2 pass1 needs -> second FFT runs on LDS-resident data.
// R12 lesson: grid.sync() costs ~100us/sync on MI355X — never again.

constexpr int N_AUDIO = 480000;
constexpr int M_FFT   = 1048576;      // 2^20

constexpr size_t OFF_C0   = 0;                    // 8 MB float2
constexpr size_t OFF_C1   = (size_t)M_FFT * 8;    // 8 MB float2
constexpr size_t OFF_SLOT = OFF_C1 + (size_t)M_FFT * 8;   // u32

#define SW(i) ((i) + ((i) >> 4))      // LDS pad swizzle
constexpr int LSZ = 1088;             // SW(1023)=1086

// ---- compile-time twiddle ROM (constexpr Taylor, double precision) ----
struct F2 { float x, y; };
constexpr double D_PI = 3.14159265358979323846264338327950288;
constexpr double tay_sin(double x) {
    double t = x, s = x, x2 = x * x;
    for (int k = 1; k <= 11; ++k) { t *= -x2 / (double)((2 * k) * (2 * k + 1)); s += t; }
    return s;
}
constexpr double tay_cos(double x) {
    double t = 1.0, s = 1.0, x2 = x * x;
    for (int k = 1; k <= 11; ++k) { t *= -x2 / (double)((2 * k - 1) * (2 * k)); s += t; }
    return s;
}
struct Tab { F2 v[1024]; };
constexpr Tab make_t1() {   // W_1024^j, arg centered to [-pi,pi)
    Tab tb{};
    for (int j = 0; j < 1024; ++j) {
        int jj = (j < 512) ? j : j - 1024;
        double a = -2.0 * D_PI * (double)jj / 1024.0;
        tb.v[j] = F2{(float)tay_cos(a), (float)tay_sin(a)};
    }
    return tb;
}
constexpr Tab make_t2() {   // W_M^j
    Tab tb{};
    for (int j = 0; j < 1024; ++j) {
        double a = -2.0 * D_PI * (double)j / 1048576.0;
        tb.v[j] = F2{(float)tay_cos(a), (float)tay_sin(a)};
    }
    return tb;
}
__device__ constexpr Tab ROM_T1 = make_t1();
__device__ constexpr Tab ROM_T2 = make_t2();

__device__ __forceinline__ float2 ldrom(const Tab& tb, int i) {
    F2 f = tb.v[i];
    return make_float2(f.x, f.y);
}
__device__ __forceinline__ float2 cmul(float2 a, float2 b) {
    return make_float2(a.x * b.x - a.y * b.y, a.x * b.y + a.y * b.x);
}
__device__ __forceinline__ void stage_tabs(float2* lt1, float2* lt2, int t) {
    #pragma unroll
    for (int q = 0; q < 4; ++q) {
        int i = t + 256 * q;
        lt1[i] = ldrom(ROM_T1, i);
        lt2[i] = ldrom(ROM_T2, i);
    }
}

// Radix-4 Stockham FFT-1024, 2 rows, 256 threads, 5 stages, result in B0.
__device__ __forceinline__ void fft1024_r4(float2 (*A0)[LSZ], float2 (*B0)[LSZ],
                                           const float2* lt1, int t) {
    float2 (*A)[LSZ] = A0;
    float2 (*B)[LSZ] = B0;
    #pragma unroll
    for (int s = 0; s < 5; ++s) {
        const int L  = 1 << (2 * s);
        const int k  = t & (L - 1);
        const int p0 = 4 * t - 3 * k;
        const float2 w  = lt1[k << (9 - 2 * s)];   // e^{-2pi i k/(2L)}
        const float2 w2 = lt1[k << (8 - 2 * s)];   // e^{-2pi i k/(4L)}
        #pragma unroll
        for (int j = 0; j < 2; ++j) {
            float2 x0 = A[j][SW(t)];
            float2 x2 = A[j][SW(t + 256)];
            float2 x1 = A[j][SW(t + 512)];
            float2 x3 = A[j][SW(t + 768)];
            float2 wx1 = cmul(w, x1), wx3 = cmul(w, x3);
            float2 u0 = make_float2(x0.x + wx1.x, x0.y + wx1.y);
            float2 u1 = make_float2(x0.x - wx1.x, x0.y - wx1.y);
            float2 u2 = make_float2(x2.x + wx3.x, x2.y + wx3.y);
            float2 u3 = make_float2(x2.x - wx3.x, x2.y - wx3.y);
            float2 a2 = cmul(w2, u2);
            float2 a3 = cmul(w2, u3);
            B[j][SW(p0)]         = make_float2(u0.x + a2.x, u0.y + a2.y);
            B[j][SW(p0 + L)]     = make_float2(u1.x + a3.y, u1.y - a3.x); // u1 - i*a3
            B[j][SW(p0 + 2*L)]   = make_float2(u0.x - a2.x, u0.y - a2.y);
            B[j][SW(p0 + 3*L)]   = make_float2(u1.x - a3.y, u1.y + a3.x); // u1 + i*a3
        }
        __syncthreads();
        float2 (*tmp)[LSZ] = A; A = B; B = tmp;
    }
}

// ---- kernel A: transform-1 pass1 + input pack. 2 rows/block, grid 512.
__global__ __launch_bounds__(256) void kA(const float* __restrict__ a,
                                          const float* __restrict__ b,
                                          float2* __restrict__ outb,
                                          u32* __restrict__ slot) {
    __shared__ float2 buf0[2][LSZ], buf1[2][LSZ], lt1[1024], lt2[1024];
    const int t  = threadIdx.x;
    const int r0 = blockIdx.x * 2;
    if (blockIdx.x == 0 && t == 0) *slot = 0u;
    stage_tabs(lt1, lt2, t);
    #pragma unroll
    for (int q = 0; q < 4; ++q) {
        int c = t + 256 * q;
        int base = c * 1024 + r0;
        float2 av = make_float2(0.f, 0.f), bv = make_float2(0.f, 0.f);
        if (c < 468 || (c == 468 && r0 < 768)) av = *(const float2*)(a + base);
        if (c < 234 || (c == 234 && r0 < 384)) bv = *(const float2*)(b + base);
        buf0[0][SW(c)] = make_float2(av.x, bv.x);
        buf0[1][SW(c)] = make_float2(av.y, bv.y);
    }
    __syncthreads();
    fft1024_r4(buf0, buf1, lt1, t);
    #pragma unroll
    for (int q = 0; q < 4; ++q) {
        int k1 = t + 256 * q;
        #pragma unroll
        for (int j = 0; j < 2; ++j) {
            int e = (r0 + j) * k1;                        // < 2^20
            float2 w = cmul(lt1[e >> 10], lt2[e & 1023]); // W_M^e
            outb[(r0 + j) * 1024 + k1] = cmul(w, buf1[j][SW(k1)]);
        }
    }
}

// ---- kernel BC: transform-1 pass2 + pointwise + transform-2 pass1. grid 512.
// Block bidx: Hermitian col pair {cA,cB} = {bidx, 1024-bidx} ({0,512} for bidx 0).
// After pointwise, LDS holds spec rows cA,cB == transform-2 pass1 rows cA,cB.
__global__ __launch_bounds__(256) void kBC(const float2* __restrict__ in,
                                           float2* __restrict__ outb) {
    __shared__ float2 buf0[2][LSZ], buf1[2][LSZ], lt1[1024], lt2[1024];
    const int t = threadIdx.x;
    const int bidx = blockIdx.x;
    const int cA = (bidx == 0) ? 0   : bidx;
    const int cB = (bidx == 0) ? 512 : 1024 - bidx;
    stage_tabs(lt1, lt2, t);
    #pragma unroll
    for (int q = 0; q < 4; ++q) {
        int r = t + 256 * q;
        buf0[0][SW(r)] = in[r * 1024 + cA];
        buf0[1][SW(r)] = in[r * 1024 + cB];
    }
    __syncthreads();
    fft1024_r4(buf0, buf1, lt1, t);                       // Z cols in buf1
    const float invM = 1.0f / 1048576.0f;
    #pragma unroll
    for (int q = 0; q < 4; ++q) {
        int k2 = t + 256 * q;
        #pragma unroll
        for (int j = 0; j < 2; ++j) {
            float2 z1 = buf1[j][SW(k2)];                  // Z[f], f = c_j + 1024*k2
            float2 z2;                                    // Z[M-f]
            if (bidx == 0) z2 = (j == 0) ? buf1[0][SW((1024 - k2) & 1023)]
                                         : buf1[1][SW(1023 - k2)];
            else           z2 = buf1[j ^ 1][SW(1023 - k2)];
            float2 Af  = make_float2(0.5f * (z1.x + z2.x), 0.5f * (z1.y - z2.y));
            float2 cBf = make_float2(0.5f * (z1.y + z2.y), 0.5f * (z1.x - z2.x)); // conj(B)
            float2 S   = cmul(Af, cBf);
            buf0[j][SW(k2)] = make_float2(S.x * invM, -S.y * invM);   // conj(S)/M
        }
    }
    __syncthreads();
    fft1024_r4(buf0, buf1, lt1, t);                       // transform-2 pass1 FFT
    #pragma unroll
    for (int q = 0; q < 4; ++q) {
        int k1 = t + 256 * q;
        #pragma unroll
        for (int j = 0; j < 2; ++j) {
            int cc = (j == 0) ? cA : cB;                  // s-layout row index
            int e  = cc * k1;                             // <= 1023*1023 < 2^20
            float2 w = cmul(lt1[e >> 10], lt2[e & 1023]);
            outb[cc * 1024 + k1] = cmul(w, buf1[j][SW(k1)]);
        }
    }
}

// ---- kernel D: transform-2 pass2, cols {c0,c0+1}; rawT (transposed) + abs-max. grid 512.
__global__ __launch_bounds__(256) void kD(const float2* __restrict__ in,
                                          float* __restrict__ rawT,
                                          u32* __restrict__ slot) {
    __shared__ float2 buf0[2][LSZ], buf1[2][LSZ], lt1[1024];
    __shared__ float wmax[4];
    const int t  = threadIdx.x;
    const int c0 = blockIdx.x * 2;
    #pragma unroll
    for (int q = 0; q < 4; ++q) { int i = t + 256 * q; lt1[i] = ldrom(ROM_T1, i); }
    #pragma unroll
    for (int q = 0; q < 4; ++q) {
        int r = t + 256 * q;
        float4 v = *(const float4*)(in + (size_t)r * 1024 + c0);
        buf0[0][SW(r)] = make_float2(v.x, v.y);
        buf0[1][SW(r)] = make_float2(v.z, v.w);
    }
    __syncthreads();
    fft1024_r4(buf0, buf1, lt1, t);
    float m = 0.0f;
    #pragma unroll
    for (int q = 0; q < 4; ++q) {
        int k2 = t + 256 * q;
        #pragma unroll
        for (int j = 0; j < 2; ++j) {
            int ot = c0 + j + (k2 << 10);
            if (ot < N_AUDIO) {
                float v = buf1[j][SW(k2)].x;
                rawT[(c0 + j) * 512 + k2] = v;       // contiguous along k2
                m = fmaxf(m, fabsf(v));
            }
        }
    }
    for (int off = 32; off > 0; off >>= 1) m = fmaxf(m, __shfl_down(m, off, 64));
    if ((t & 63) == 0) wmax[t >> 6] = m;
    __syncthreads();
    if (t == 0) {
        float bm = fmaxf(fmaxf(wmax[0], wmax[1]), fmaxf(wmax[2], wmax[3]));
        atomicMax(slot, __float_as_uint(bm));
    }
}

// ---- kernel E: tiled transpose + normalize. 64x64 tiles, coalesced both sides. grid 128.
__global__ __launch_bounds__(256) void kE(const float* __restrict__ rawT,
                                          const u32* __restrict__ slot,
                                          float* __restrict__ out) {
    __shared__ float tile[64][65];
    const int t  = threadIdx.x;
    const int c0 = (blockIdx.x & 15) * 64;        // 16 c-tiles
    const int k0 = (blockIdx.x >> 4) * 64;        // 8 k2-tiles
    const int cl = t >> 2, ch = (t & 3) * 16;
    #pragma unroll
    for (int i = 0; i < 4; ++i) {
        float4 v = *(const float4*)(rawT + (size_t)(c0 + cl) * 512 + k0 + ch + i * 4);
        tile[cl][ch + i * 4 + 0] = v.x;
        tile[cl][ch + i * 4 + 1] = v.y;
        tile[cl][ch + i * 4 + 2] = v.z;
        tile[cl][ch + i * 4 + 3] = v.w;
    }
    __syncthreads();
    const float inv = 1.0f / __uint_as_float(*slot);
    const int cw = t & 63, w = t >> 6;
    #pragma unroll
    for (int q = 0; q < 16; ++q) {
        int kk = q * 4 + w;
        int o = (k0 + kk) * 1024 + c0 + cw;
        if (o < N_AUDIO) out[o] = tile[cw][kk] * inv;
    }
}

extern "C" void kernel_launch(void* const* d_in, const int* in_sizes, int n_in,
                              void* d_out, int out_size, void* d_ws, size_t ws_size,
                              hipStream_t stream) {
    const float* audio = (const float*)d_in[0];
    const float* ir    = (const float*)d_in[1];
    float* out = (float*)d_out;

    char* ws = (char*)d_ws;
    float2* cb0 = (float2*)(ws + OFF_C0);
    float2* cb1 = (float2*)(ws + OFF_C1);
    u32*    slot = (u32*)(ws + OFF_SLOT);

    kA<<<512, 256, 0, stream>>>(audio, ir, cb1, slot);          // pack + T1 rows
    kBC<<<512, 256, 0, stream>>>(cb1, cb0);                     // T1 cols + pw + T2 rows
    kD<<<512, 256, 0, stream>>>(cb0, (float*)cb1, slot);        // T2 cols + absmax -> rawT
    kE<<<128, 256, 0, stream>>>((const float*)cb1, slot, out);  // transpose + scale
}

// Round 16
// 98.416 us; speedup vs baseline: 5.6668x; 1.0611x over previous
//
#include <hip/hip_runtime.h>

typedef unsigned int u32;

// ---------------- FFT-based reverb (R16: half-size real IFFT for transform-2) ----------------
// out[t] = sum_k audio[t+k] ir[k], t in [0,480000); M = 2^20 circular == linear.
// z = a + i*b ; Z1 = F[z]; A=(Z1[f]+conj(Z1[M-f]))/2, B=(Z1[f]-conj(Z1[M-f]))/(2i)
// X = S = A*conj(B)  (Hermitian). y = IDFT_M(X) real.
// Real-IFFT trick: w[p] = y[2p]+i*y[2p+1]; Z[k] = A_k + B_k, k<N2=M/2:
//   A_k = (X[k]+conj(X[N2-k]))/2,  B_k = (i/2)*conj(W_M^k)*(X[k]-conj(X[N2-k]))
//   w = IDFT_N2(Z) = conj(FFT_N2(conj(Z)/N2)); y[2p]=Re W'[p], y[2p+1]=-Im W'[p].
// Four-step T1: M=1024x1024 (verified R8-R15). Transform-2': N2 = 512(a) x 1024(b),
// k = a*1024 + b: pass1 FFT_512 over a (fused in kBC — block owns rows {cc,1024-cc}
// which contain both X[k] and X[N2-k]!), pass2 FFT_1024 over b (kD, grid halved).
// R12 lesson: no grid.sync on MI355X.

constexpr int N_AUDIO = 480000;
constexpr int M_FFT   = 1048576;      // 2^20

constexpr size_t OFF_C0   = 0;                    // 8 MB float2
constexpr size_t OFF_C1   = (size_t)M_FFT * 8;    // 8 MB float2
constexpr size_t OFF_SLOT = OFF_C1 + (size_t)M_FFT * 8;   // u32

#define SW(i) ((i) + ((i) >> 4))      // LDS pad swizzle
constexpr int LSZ = 1088;             // SW(1023)=1086

// ---- compile-time twiddle ROM (constexpr Taylor, double precision) ----
struct F2 { float x, y; };
constexpr double D_PI = 3.14159265358979323846264338327950288;
constexpr double tay_sin(double x) {
    double t = x, s = x, x2 = x * x;
    for (int k = 1; k <= 11; ++k) { t *= -x2 / (double)((2 * k) * (2 * k + 1)); s += t; }
    return s;
}
constexpr double tay_cos(double x) {
    double t = 1.0, s = 1.0, x2 = x * x;
    for (int k = 1; k <= 11; ++k) { t *= -x2 / (double)((2 * k - 1) * (2 * k)); s += t; }
    return s;
}
struct Tab { F2 v[1024]; };
constexpr Tab make_t1() {   // W_1024^j, arg centered to [-pi,pi)
    Tab tb{};
    for (int j = 0; j < 1024; ++j) {
        int jj = (j < 512) ? j : j - 1024;
        double a = -2.0 * D_PI * (double)jj / 1024.0;
        tb.v[j] = F2{(float)tay_cos(a), (float)tay_sin(a)};
    }
    return tb;
}
constexpr Tab make_t2() {   // W_M^j
    Tab tb{};
    for (int j = 0; j < 1024; ++j) {
        double a = -2.0 * D_PI * (double)j / 1048576.0;
        tb.v[j] = F2{(float)tay_cos(a), (float)tay_sin(a)};
    }
    return tb;
}
__device__ constexpr Tab ROM_T1 = make_t1();
__device__ constexpr Tab ROM_T2 = make_t2();

__device__ __forceinline__ float2 ldrom(const Tab& tb, int i) {
    F2 f = tb.v[i];
    return make_float2(f.x, f.y);
}
__device__ __forceinline__ float2 cmul(float2 a, float2 b) {
    return make_float2(a.x * b.x - a.y * b.y, a.x * b.y + a.y * b.x);
}
__device__ __forceinline__ void stage_tabs(float2* lt1, float2* lt2, int t) {
    #pragma unroll
    for (int q = 0; q < 4; ++q) {
        int i = t + 256 * q;
        lt1[i] = ldrom(ROM_T1, i);
        lt2[i] = ldrom(ROM_T2, i);
    }
}

// Radix-4 Stockham FFT-1024, 2 rows, 256 threads, 5 stages, result in B0. (validated R10-R15)
__device__ __forceinline__ void fft1024_r4(float2 (*A0)[LSZ], float2 (*B0)[LSZ],
                                           const float2* lt1, int t) {
    float2 (*A)[LSZ] = A0;
    float2 (*B)[LSZ] = B0;
    #pragma unroll
    for (int s = 0; s < 5; ++s) {
        const int L  = 1 << (2 * s);
        const int k  = t & (L - 1);
        const int p0 = 4 * t - 3 * k;
        const float2 w  = lt1[k << (9 - 2 * s)];   // e^{-2pi i k/(2L)}
        const float2 w2 = lt1[k << (8 - 2 * s)];   // e^{-2pi i k/(4L)}
        #pragma unroll
        for (int j = 0; j < 2; ++j) {
            float2 x0 = A[j][SW(t)];
            float2 x2 = A[j][SW(t + 256)];
            float2 x1 = A[j][SW(t + 512)];
            float2 x3 = A[j][SW(t + 768)];
            float2 wx1 = cmul(w, x1), wx3 = cmul(w, x3);
            float2 u0 = make_float2(x0.x + wx1.x, x0.y + wx1.y);
            float2 u1 = make_float2(x0.x - wx1.x, x0.y - wx1.y);
            float2 u2 = make_float2(x2.x + wx3.x, x2.y + wx3.y);
            float2 u3 = make_float2(x2.x - wx3.x, x2.y - wx3.y);
            float2 a2 = cmul(w2, u2);
            float2 a3 = cmul(w2, u3);
            B[j][SW(p0)]         = make_float2(u0.x + a2.x, u0.y + a2.y);
            B[j][SW(p0 + L)]     = make_float2(u1.x + a3.y, u1.y - a3.x); // u1 - i*a3
            B[j][SW(p0 + 2*L)]   = make_float2(u0.x - a2.x, u0.y - a2.y);
            B[j][SW(p0 + 3*L)]   = make_float2(u1.x - a3.y, u1.y + a3.x); // u1 + i*a3
        }
        __syncthreads();
        float2 (*tmp)[LSZ] = A; A = B; B = tmp;
    }
}

// Radix-4x4 + radix-2 Stockham FFT-512 on TWO independent 512-pt arrays.
// 256 threads: col j = t>>7, tt = t&127 (one butterfly per stage per thread).
// Twiddle shifts identical to 1024 case (depend only on L). Result in B0.
__device__ __forceinline__ void fft512_r4(float2 (*A0)[LSZ], float2 (*B0)[LSZ],
                                          const float2* lt1, int t) {
    float2 (*A)[LSZ] = A0;
    float2 (*B)[LSZ] = B0;
    const int j  = t >> 7;
    const int tt = t & 127;
    #pragma unroll
    for (int s = 0; s < 4; ++s) {
        const int L  = 1 << (2 * s);
        const int k  = tt & (L - 1);
        const int p0 = 4 * tt - 3 * k;
        const float2 w  = lt1[k << (9 - 2 * s)];
        const float2 w2 = lt1[k << (8 - 2 * s)];
        float2 x0 = A[j][SW(tt)];
        float2 x2 = A[j][SW(tt + 128)];
        float2 x1 = A[j][SW(tt + 256)];
        float2 x3 = A[j][SW(tt + 384)];
        float2 wx1 = cmul(w, x1), wx3 = cmul(w, x3);
        float2 u0 = make_float2(x0.x + wx1.x, x0.y + wx1.y);
        float2 u1 = make_float2(x0.x - wx1.x, x0.y - wx1.y);
        float2 u2 = make_float2(x2.x + wx3.x, x2.y + wx3.y);
        float2 u3 = make_float2(x2.x - wx3.x, x2.y - wx3.y);
        float2 a2 = cmul(w2, u2);
        float2 a3 = cmul(w2, u3);
        B[j][SW(p0)]       = make_float2(u0.x + a2.x, u0.y + a2.y);
        B[j][SW(p0 + L)]   = make_float2(u1.x + a3.y, u1.y - a3.x);
        B[j][SW(p0 + 2*L)] = make_float2(u0.x - a2.x, u0.y - a2.y);
        B[j][SW(p0 + 3*L)] = make_float2(u1.x - a3.y, u1.y + a3.x);
        __syncthreads();
        float2 (*tmp)[LSZ] = A; A = B; B = tmp;
    }
    // final radix-2 stage, L=256: 256 butterflies/col, 2 per thread
    #pragma unroll
    for (int h = 0; h < 2; ++h) {
        int i = tt + 128 * h;                   // 0..255, k = i
        float2 x0 = A[j][SW(i)];
        float2 x1 = A[j][SW(i + 256)];
        float2 w  = lt1[i << 1];                // e^{-2pi i i/512}
        float2 wx = cmul(w, x1);
        B[j][SW(i)]       = make_float2(x0.x + wx.x, x0.y + wx.y);
        B[j][SW(i + 256)] = make_float2(x0.x - wx.x, x0.y - wx.y);
    }
    __syncthreads();
}

// ---- kernel A: transform-1 pass1 + input pack. 2 rows/block, grid 512. (validated)
__global__ __launch_bounds__(256) void kA(const float* __restrict__ a,
                                          const float* __restrict__ b,
                                          float2* __restrict__ outb,
                                          u32* __restrict__ slot) {
    __shared__ float2 buf0[2][LSZ], buf1[2][LSZ], lt1[1024], lt2[1024];
    const int t  = threadIdx.x;
    const int r0 = blockIdx.x * 2;
    if (blockIdx.x == 0 && t == 0) *slot = 0u;
    stage_tabs(lt1, lt2, t);
    #pragma unroll
    for (int q = 0; q < 4; ++q) {
        int c = t + 256 * q;
        int base = c * 1024 + r0;
        float2 av = make_float2(0.f, 0.f), bv = make_float2(0.f, 0.f);
        if (c < 468 || (c == 468 && r0 < 768)) av = *(const float2*)(a + base);
        if (c < 234 || (c == 234 && r0 < 384)) bv = *(const float2*)(b + base);
        buf0[0][SW(c)] = make_float2(av.x, bv.x);
        buf0[1][SW(c)] = make_float2(av.y, bv.y);
    }
    __syncthreads();
    fft1024_r4(buf0, buf1, lt1, t);
    #pragma unroll
    for (int q = 0; q < 4; ++q) {
        int k1 = t + 256 * q;
        #pragma unroll
        for (int j = 0; j < 2; ++j) {
            int e = (r0 + j) * k1;                        // < 2^20
            float2 w = cmul(lt1[e >> 10], lt2[e & 1023]); // W_M^e
            outb[(r0 + j) * 1024 + k1] = cmul(w, buf1[j][SW(k1)]);
        }
    }
}

// ---- kernel BC: T1 pass2 + pointwise + real-IFFT pack + T2' pass1 (FFT_512). grid 512.
// Block bidx owns Hermitian col pair {cA,cB} = {bidx, 1024-bidx} ({0,512} for 0):
// holds X[f] for f = cc + 1024*k2 AND X[N2-k] for its V-columns -> fully fused.
__global__ __launch_bounds__(256) void kBC(const float2* __restrict__ in,
                                           float2* __restrict__ gbuf) {
    __shared__ float2 buf0[2][LSZ], buf1[2][LSZ], lt1[1024], lt2[1024];
    const int t = threadIdx.x;
    const int bidx = blockIdx.x;
    const int cA = (bidx == 0) ? 0   : bidx;
    const int cB = (bidx == 0) ? 512 : 1024 - bidx;
    stage_tabs(lt1, lt2, t);
    #pragma unroll
    for (int q = 0; q < 4; ++q) {
        int r = t + 256 * q;
        buf0[0][SW(r)] = in[r * 1024 + cA];
        buf0[1][SW(r)] = in[r * 1024 + cB];
    }
    __syncthreads();
    fft1024_r4(buf0, buf1, lt1, t);                       // Z1 cols in buf1
    // pointwise: X = S_raw = A*conj(B), write to buf0 (reads buf1 only)
    #pragma unroll
    for (int q = 0; q < 4; ++q) {
        int k2 = t + 256 * q;
        #pragma unroll
        for (int j = 0; j < 2; ++j) {
            float2 z1 = buf1[j][SW(k2)];
            float2 z2;
            if (bidx == 0) z2 = (j == 0) ? buf1[0][SW((1024 - k2) & 1023)]
                                         : buf1[1][SW(1023 - k2)];
            else           z2 = buf1[j ^ 1][SW(1023 - k2)];
            float2 Af  = make_float2(0.5f * (z1.x + z2.x), 0.5f * (z1.y - z2.y));
            float2 cBf = make_float2(0.5f * (z1.y + z2.y), 0.5f * (z1.x - z2.x));
            buf0[j][SW(k2)] = cmul(Af, cBf);              // X (no scale, no conj)
        }
    }
    __syncthreads();
    // real-IFFT pack: q[k] = conj(Z[k])/N2 into buf1[j][0..511], k = b_j + 1024*k2v
    const float invN2 = 1.0f / 524288.0f;
    #pragma unroll
    for (int j = 0; j < 2; ++j) {
        const int bcol = (j == 0) ? cA : cB;
        const float2 wb = lt2[bcol];                      // W_M^{bcol}
        #pragma unroll
        for (int h = 0; h < 2; ++h) {
            int k2v = t + 256 * h;                        // 0..511
            float2 z1 = buf0[j][SW(k2v)];                 // X[k]
            int jr, p2;
            if (bidx == 0) { jr = j; p2 = (j == 0) ? (512 - k2v) : (511 - k2v); }
            else           { jr = j ^ 1; p2 = 511 - k2v; }
            float2 z2c = buf0[jr][SW(p2)];                // X[N2-k]
            z2c.y = -z2c.y;                               // conj
            float2 A2 = make_float2(0.5f * (z1.x + z2c.x), 0.5f * (z1.y + z2c.y));
            float2 D2 = make_float2(0.5f * (z1.x - z2c.x), 0.5f * (z1.y - z2c.y));
            float2 cw = cmul(lt1[k2v], wb);               // W_M^k
            float2 iB = cmul(make_float2(cw.y, cw.x), D2);// i*conj(cw)*D
            float2 Z  = make_float2(A2.x + iB.x, A2.y + iB.y);
            buf1[j][SW(k2v)] = make_float2(Z.x * invN2, -Z.y * invN2);  // conj(Z)/N2
        }
    }
    __syncthreads();
    fft512_r4(buf1, buf0, lt1, t);                        // G in buf0[j][0..511]
    // twiddle W_N2^{b*k1} = W_M^{2*b*k1}, store gbuf[b*512 + k1]
    const int jc = t >> 7, tt = t & 127;
    const int bcol = (jc == 0) ? cA : cB;
    #pragma unroll
    for (int u = 0; u < 4; ++u) {
        int k1 = tt + 128 * u;                            // 0..511
        int e2 = 2 * bcol * k1;                           // <= 1045506 < 2^20
        float2 w = cmul(lt1[e2 >> 10], lt2[e2 & 1023]);
        gbuf[bcol * 512 + k1] = cmul(w, buf0[jc][SW(k1)]);
    }
}

// ---- kernel D: T2' pass2 (FFT_1024 over b), k1' pair {2q,2q+1}. grid 256.
// Writes rawT2[k1'*1024+k2'] = (y_even, y_odd) = (Re W', -Im W') + abs-max.
__global__ __launch_bounds__(256) void kD(const float2* __restrict__ gbuf,
                                          float2* __restrict__ rawT2,
                                          u32* __restrict__ slot) {
    __shared__ float2 buf0[2][LSZ], buf1[2][LSZ], lt1[1024];
    __shared__ float wmax[4];
    const int t = threadIdx.x;
    const int qb = blockIdx.x;                            // k1' = 2qb, 2qb+1
    #pragma unroll
    for (int q = 0; q < 4; ++q) { int i = t + 256 * q; lt1[i] = ldrom(ROM_T1, i); }
    #pragma unroll
    for (int q = 0; q < 4; ++q) {
        int b = t + 256 * q;
        float4 v = *(const float4*)(gbuf + (size_t)b * 512 + 2 * qb);
        buf0[0][SW(b)] = make_float2(v.x, v.y);
        buf0[1][SW(b)] = make_float2(v.z, v.w);
    }
    __syncthreads();
    fft1024_r4(buf0, buf1, lt1, t);                       // W' in buf1
    float m = 0.0f;
    #pragma unroll
    for (int q = 0; q < 4; ++q) {
        int k2 = t + 256 * q;
        #pragma unroll
        for (int j = 0; j < 2; ++j) {
            int k1 = 2 * qb + j;
            int to = 2 * k1 + 1024 * k2;                  // even output index
            if (to < N_AUDIO) {
                float2 v = buf1[j][SW(k2)];
                rawT2[k1 * 1024 + k2] = make_float2(v.x, -v.y);
                m = fmaxf(m, fmaxf(fabsf(v.x), fabsf(v.y)));
            }
        }
    }
    for (int off = 32; off > 0; off >>= 1) m = fmaxf(m, __shfl_down(m, off, 64));
    if ((t & 63) == 0) wmax[t >> 6] = m;
    __syncthreads();
    if (t == 0) {
        float bm = fmaxf(fmaxf(wmax[0], wmax[1]), fmaxf(wmax[2], wmax[3]));
        atomicMax(slot, __float_as_uint(bm));
    }
}

// ---- kernel E: tiled transpose (512 x 1024 float2) + normalize. grid 128.
__global__ __launch_bounds__(256) void kE(const float2* __restrict__ rawT2,
                                          const u32* __restrict__ slot,
                                          float* __restrict__ out) {
    __shared__ float2 tile[64][65];
    const int t  = threadIdx.x;
    const int K0 = (blockIdx.x & 7) * 64;         // k1' tile (8)
    const int Q0 = (blockIdx.x >> 3) * 64;        // k2' tile (16)
    #pragma unroll
    for (int i = 0; i < 16; ++i) {
        int idx = t + 256 * i;
        int row = idx >> 6, col = idx & 63;
        tile[col][row] = rawT2[(size_t)(K0 + row) * 1024 + Q0 + col];
    }
    __syncthreads();
    const float inv = 1.0f / __uint_as_float(*slot);
    #pragma unroll
    for (int i = 0; i < 16; ++i) {
        int idx = t + 256 * i;
        int cc = idx >> 6, rr = idx & 63;
        int o = (Q0 + cc) * 1024 + 2 * (K0 + rr);
        if (o < N_AUDIO) {
            float2 v = tile[cc][rr];
            *(float2*)(out + o) = make_float2(v.x * inv, v.y * inv);
        }
    }
}

extern "C" void kernel_launch(void* const* d_in, const int* in_sizes, int n_in,
                              void* d_out, int out_size, void* d_ws, size_t ws_size,
                              hipStream_t stream) {
    const float* audio = (const float*)d_in[0];
    const float* ir    = (const float*)d_in[1];
    float* out = (float*)d_out;

    char* ws = (char*)d_ws;
    float2* cb0 = (float2*)(ws + OFF_C0);
    float2* cb1 = (float2*)(ws + OFF_C1);
    u32*    slot = (u32*)(ws + OFF_SLOT);

    kA<<<512, 256, 0, stream>>>(audio, ir, cb1, slot);          // pack + T1 rows
    kBC<<<512, 256, 0, stream>>>(cb1, cb0);                     // T1 cols + pw + pack + T2' rows
    kD<<<256, 256, 0, stream>>>(cb0, cb1, slot);                // T2' cols + absmax -> rawT2
    kE<<<128, 256, 0, stream>>>((const float2*)cb1, slot, out); // transpose + scale
}